// Round 5
// baseline (141.260 us; speedup 1.0000x reference)
//
#include <hip/hip_runtime.h>
#include <math.h>

#define C_IN   256
#define C_HEAD 32
#define HW     361          // 19*19
#define NTHR   384          // 6 waves
#define CV     48
#define WSTR   264          // wtT row stride (bf16 elems), padded
#define PSTR   364          // x-tile row capacity (361 + 3 shift), multiple of 4
#define CCHUNK 32           // channels per chunk
#define QUADS  2888         // 361*32/4 — chunk is quad-exact
#define NCHUNK 8

typedef __attribute__((ext_vector_type(8))) short bf16x8;
typedef __attribute__((ext_vector_type(4))) float f32x4;

static __device__ __forceinline__ unsigned short f2bf(float f) {
    unsigned int u = __builtin_bit_cast(unsigned int, f);
    u += 0x7fffu + ((u >> 16) & 1u);          // RNE
    return (unsigned short)(u >> 16);
}

__global__ __launch_bounds__(NTHR, 3) void vh_fused(
    const float* __restrict__ x,
    const float* __restrict__ conv_w,
    const float* __restrict__ fc1_w, const float* __restrict__ fc1_b,
    const float* __restrict__ fc2_w, const float* __restrict__ fc2_b,
    const float* __restrict__ fc3_w, const float* __restrict__ fc3_b,
    const float* __restrict__ sc_w,  const float* __restrict__ sc_b,
    const float* __restrict__ fc4_w, const float* __restrict__ fc4_b,
    const float* __restrict__ fc5_w, const float* __restrict__ fc5_b,
    float* __restrict__ out, int B)
{
    const int b    = blockIdx.x;
    const int tid  = threadIdx.x;
    const int wave = tid >> 6;
    const int lane = tid & 63;
    const int l15  = lane & 15;
    const int g    = lane >> 4;

    __shared__ __align__(16) unsigned short wtT[C_HEAD * WSTR];      // 16.9 KB
    __shared__ __align__(16) unsigned short xs[2][CCHUNK * PSTR];    // 2 x 23.3 KB
    __shared__ float lds_psum[C_HEAD][6];
    __shared__ float lds_pmax[C_HEAD][6];
    __shared__ float vp[3 * C_HEAD];
    __shared__ float base_l[CV], dco_l[CV], f5_l[CV];

    // ---- one-time: W bf16 into LDS, [o][c] (k-contiguous for B-frag) ----
    for (int i = tid; i < C_HEAD * C_IN; i += NTHR) {
        int o = i >> 8, c = i & 255;
        wtT[o * WSTR + c] = f2bf(conv_w[i]);
    }

    const float* __restrict__ xb = x + (size_t)b * (C_IN * HW);

    float4 vreg[8];

    // issue 8 aligned float4 loads (flat-slab quads) for chunk q into vreg
    auto loadq = [&](int q) {
        #pragma unroll
        for (int itv = 0; itv < 8; ++itv) {
            int it = itv * NTHR + tid;
            if (it < QUADS)
                vreg[itv] = *(const float4*)(xb + q * (CCHUNK * HW) + it * 4);
        }
    };

    // convert + write vreg into xs[buf]; element (cl,p) at cl*PSTR + p + (cl&3)
    auto writeq = [&](int buf) {
        #pragma unroll
        for (int itv = 0; itv < 8; ++itv) {
            int it = itv * NTHR + tid;
            if (it < QUADS) {
                int fl = it * 4;
                int cl = (int)__umulhi((unsigned)fl, 11897417u);   // fl / 361
                int p0 = fl - cl * 361;
                float4 v = vreg[itv];
                unsigned short h0 = f2bf(v.x), h1 = f2bf(v.y),
                               h2 = f2bf(v.z), h3 = f2bf(v.w);
                if (p0 <= 357) {   // p0 ≡ -cl (mod 4) -> p0+(cl&3) ≡ 0 (mod 4): aligned b64
                    unsigned int lo = (unsigned)h0 | ((unsigned)h1 << 16);
                    unsigned int hi = (unsigned)h2 | ((unsigned)h3 << 16);
                    *(uint2*)&xs[buf][cl * PSTR + p0 + (cl & 3)] = make_uint2(lo, hi);
                } else {           // row-straddling quad (~1%): scalar b16 writes
                    unsigned short hh[4] = {h0, h1, h2, h3};
                    #pragma unroll
                    for (int i2 = 0; i2 < 4; ++i2) {
                        int p = p0 + i2;
                        if (p < HW)
                            xs[buf][cl * PSTR + p + (cl & 3)] = hh[i2];
                        else
                            xs[buf][(cl + 1) * PSTR + (p - HW) + ((cl + 1) & 3)] = hh[i2];
                    }
                }
            }
        }
    };

    f32x4 acc[4][2];
    #pragma unroll
    for (int mi = 0; mi < 4; ++mi)
        #pragma unroll
        for (int n = 0; n < 2; ++n)
            acc[mi][n] = (f32x4){0.f, 0.f, 0.f, 0.f};

    // prologue: stage chunk 0
    loadq(0);
    writeq(0);

    // ---- main loop: 1 barrier/chunk; loads for q+1 in flight across compute ----
    for (int q = 0; q < NCHUNK; ++q) {
        __syncthreads();               // xs[q&1] ready (and wtT on q==0)
        if (q < NCHUNK - 1) loadq(q + 1);

        bf16x8 wf[2];
        #pragma unroll
        for (int n = 0; n < 2; ++n)
            wf[n] = *(const bf16x8*)&wtT[(n * 16 + l15) * WSTR + q * 32 + g * 8];

        const unsigned short* xc = xs[q & 1];
        #pragma unroll
        for (int mi = 0; mi < 4; ++mi) {
            int p = wave * 64 + mi * 16 + l15;
            if (p >= HW) p = HW - 1;                 // clamp; masked at reduction
            bf16x8 a;
            #pragma unroll
            for (int e = 0; e < 8; ++e) {
                int cl = g * 8 + e;
                a[e] = (short)xc[cl * PSTR + p + (e & 3)];   // (cl&3)==(e&3)
            }
            acc[mi][0] = __builtin_amdgcn_mfma_f32_16x16x32_bf16(a, wf[0], acc[mi][0], 0, 0, 0);
            acc[mi][1] = __builtin_amdgcn_mfma_f32_16x16x32_bf16(a, wf[1], acc[mi][1], 0, 0, 0);
        }

        if (q < NCHUNK - 1) writeq((q + 1) & 1);
    }

    // ---- reduce over positions: lane holds D[p = wave*64+mi*16+g*4+r][o = n*16+l15] ----
    float s[2]  = {0.f, 0.f};
    float mx[2] = {-3.0e38f, -3.0e38f};
    #pragma unroll
    for (int n = 0; n < 2; ++n) {
        #pragma unroll
        for (int mi = 0; mi < 4; ++mi) {
            #pragma unroll
            for (int r = 0; r < 4; ++r) {
                int pp = wave * 64 + mi * 16 + g * 4 + r;
                float v = acc[mi][n][r];
                if (pp < HW) { s[n] += v; mx[n] = fmaxf(mx[n], v); }
            }
        }
        s[n] += __shfl_xor(s[n], 16, 64);
        s[n] += __shfl_xor(s[n], 32, 64);
        mx[n] = fmaxf(mx[n], __shfl_xor(mx[n], 16, 64));
        mx[n] = fmaxf(mx[n], __shfl_xor(mx[n], 32, 64));
    }
    if (lane < 32) {
        lds_psum[lane][wave] = (lane < 16) ? s[0] : s[1];
        lds_pmax[lane][wave] = (lane < 16) ? mx[0] : mx[1];
    }
    __syncthreads();

    if (tid < C_HEAD) {
        float ss = 0.f, mm = -3.0e38f;
        #pragma unroll
        for (int w = 0; w < 6; ++w) { ss += lds_psum[tid][w]; mm = fmaxf(mm, lds_pmax[tid][w]); }
        float mean1 = ss * (1.0f / (float)HW);
        vp[tid]              = mean1;
        vp[C_HEAD + tid]     = mean1 * ((19.0f - 9.0f) * 0.1f);
        vp[2 * C_HEAD + tid] = mm;
    }
    __syncthreads();

    // ---- heads: wave 0 ----
    if (wave == 0) {
        const int j = lane;
        float h1 = 0.f, h3 = 0.f;
        if (j < CV) {
            float a1 = fc1_b[j], a3 = fc3_b[j], a4 = fc4_b[j];
            #pragma unroll
            for (int k = 0; k < 96; ++k) {
                float v = vp[k];
                a1 = fmaf(v, fc1_w[j * 96 + k], a1);
                a3 = fmaf(v, fc3_w[j * 96 + k], a3);
                a4 = fmaf(v, fc4_w[j * 97 + k], a4);
            }
            h1 = fmaxf(a1, 0.f) * fc2_w[j];
            h3 = fmaxf(a3, 0.f) * sc_w[j];
            base_l[j] = a4;
            dco_l[j]  = fc4_w[j * 97 + 96];
            f5_l[j]   = fc5_w[j];
        }
        float s1 = h1, s3 = h3;
        #pragma unroll
        for (int off = 32; off > 0; off >>= 1) {
            s1 += __shfl_xor(s1, off, 64);
            s3 += __shfl_xor(s3, off, 64);
        }
        float game = tanhf(s1 + fc2_b[0]);
        float scal = s3 + sc_b[0];
        if (lane == 0) out[b] = game;

        float z = -3.0e38f;
        if (lane < 41) {
            float dval = (float)(lane - 20);
            float lg = fc5_b[0];
            #pragma unroll
            for (int jj = 0; jj < CV; ++jj) {
                float t2 = fmaf(dval, dco_l[jj], base_l[jj]);
                t2 = fmaxf(t2, 0.f);
                lg = fmaf(t2, f5_l[jj], lg);
            }
            z = lg * scal;
        }
        float mz = z;
        #pragma unroll
        for (int off = 32; off > 0; off >>= 1) mz = fmaxf(mz, __shfl_xor(mz, off, 64));
        float e = (lane < 41) ? expf(z - mz) : 0.f;
        float se = e;
        #pragma unroll
        for (int off = 32; off > 0; off >>= 1) se += __shfl_xor(se, off, 64);
        if (lane < 41) out[B + b * 41 + lane] = e / se;
    }
}

extern "C" void kernel_launch(void* const* d_in, const int* in_sizes, int n_in,
                              void* d_out, int out_size, void* d_ws, size_t ws_size,
                              hipStream_t stream) {
    const float* x      = (const float*)d_in[0];
    const float* conv_w = (const float*)d_in[1];
    const float* fc1_w  = (const float*)d_in[2];
    const float* fc1_b  = (const float*)d_in[3];
    const float* fc2_w  = (const float*)d_in[4];
    const float* fc2_b  = (const float*)d_in[5];
    const float* fc3_w  = (const float*)d_in[6];
    const float* fc3_b  = (const float*)d_in[7];
    const float* sc_w   = (const float*)d_in[8];
    const float* sc_b   = (const float*)d_in[9];
    const float* fc4_w  = (const float*)d_in[10];
    const float* fc4_b  = (const float*)d_in[11];
    const float* fc5_w  = (const float*)d_in[12];
    const float* fc5_b  = (const float*)d_in[13];
    float* out = (float*)d_out;

    int B = in_sizes[0] / (C_IN * HW);

    vh_fused<<<dim3(B), dim3(NTHR), 0, stream>>>(
        x, conv_w, fc1_w, fc1_b, fc2_w, fc2_b, fc3_w, fc3_b,
        sc_w, sc_b, fc4_w, fc4_b, fc5_w, fc5_b, out, B);
}

// Round 6
// 117.359 us; speedup vs baseline: 1.2037x; 1.2037x over previous
//
#include <hip/hip_runtime.h>
#include <math.h>

#define C_IN   256
#define C_HEAD 32
#define HW     361          // 19*19
#define NTHR   384          // 6 waves
#define CV     48
#define WSTR   264          // wtT row stride (bf16 elems), padded: 2-way b128 banks = free

typedef __attribute__((ext_vector_type(8))) short bf16x8;
typedef __attribute__((ext_vector_type(4))) float f32x4;

static __device__ __forceinline__ unsigned short f2bf(float f) {
    unsigned int u = __builtin_bit_cast(unsigned int, f);
    u += 0x7fffu + ((u >> 16) & 1u);          // RNE
    return (unsigned short)(u >> 16);
}

__global__ __launch_bounds__(NTHR, 3) void vh_fused(
    const float* __restrict__ x,
    const float* __restrict__ conv_w,
    const float* __restrict__ fc1_w, const float* __restrict__ fc1_b,
    const float* __restrict__ fc2_w, const float* __restrict__ fc2_b,
    const float* __restrict__ fc3_w, const float* __restrict__ fc3_b,
    const float* __restrict__ sc_w,  const float* __restrict__ sc_b,
    const float* __restrict__ fc4_w, const float* __restrict__ fc4_b,
    const float* __restrict__ fc5_w, const float* __restrict__ fc5_b,
    float* __restrict__ out, int B)
{
    const int b    = blockIdx.x;
    const int tid  = threadIdx.x;
    const int wave = tid >> 6;
    const int lane = tid & 63;
    const int l15  = lane & 15;
    const int g    = lane >> 4;

    __shared__ __align__(16) unsigned short wtT[C_HEAD * WSTR]; // W [o][c] bf16, 16.9 KB
    __shared__ float lds_psum[C_HEAD][6];
    __shared__ float lds_pmax[C_HEAD][6];
    __shared__ float vp[3 * C_HEAD];
    __shared__ float base_l[CV], dco_l[CV], f5_l[CV];

    // ---- one-time: W as bf16 into LDS, [o][c] (k-contiguous for B-frag) ----
    for (int i = tid; i < C_HEAD * C_IN; i += NTHR) {
        int o = i >> 8, c = i & 255;
        wtT[o * WSTR + c] = f2bf(conv_w[i]);
    }
    __syncthreads();

    f32x4 acc[4][2];
    #pragma unroll
    for (int mi = 0; mi < 4; ++mi)
        #pragma unroll
        for (int n = 0; n < 2; ++n)
            acc[mi][n] = (f32x4){0.f, 0.f, 0.f, 0.f};

    const float* __restrict__ xb = x + (size_t)b * (C_IN * HW);

    // lane base offsets (elements): c-part g*8*HW folded in; p clamped (masked later)
    unsigned labase[4];
    #pragma unroll
    for (int mi = 0; mi < 4; ++mi) {
        int p = wave * 64 + mi * 16 + l15;
        if (p >= HW) p = HW - 1;
        labase[mi] = (unsigned)(g * 8 * HW + p);
    }

    float rawA[32], rawB[32];

    // issue 32 independent loads for chunk t into a named register bank
    auto issue = [&](int t, float (&bank)[32]) {
        #pragma unroll
        for (int mi = 0; mi < 4; ++mi)
            #pragma unroll
            for (int e = 0; e < 8; ++e)
                bank[mi * 8 + e] = xb[labase[mi] + (unsigned)((t * 32 + e) * HW)];
    };

    // convert chunk t's bank to bf16 fragments and run its 8 MFMAs
    auto step = [&](int t, float (&bank)[32]) {
        bf16x8 wf0 = *(const bf16x8*)&wtT[(      l15) * WSTR + t * 32 + g * 8];
        bf16x8 wf1 = *(const bf16x8*)&wtT[(16 + l15) * WSTR + t * 32 + g * 8];
        #pragma unroll
        for (int mi = 0; mi < 4; ++mi) {
            uint4 u;
            u.x = (unsigned)f2bf(bank[mi*8+0]) | ((unsigned)f2bf(bank[mi*8+1]) << 16);
            u.y = (unsigned)f2bf(bank[mi*8+2]) | ((unsigned)f2bf(bank[mi*8+3]) << 16);
            u.z = (unsigned)f2bf(bank[mi*8+4]) | ((unsigned)f2bf(bank[mi*8+5]) << 16);
            u.w = (unsigned)f2bf(bank[mi*8+6]) | ((unsigned)f2bf(bank[mi*8+7]) << 16);
            bf16x8 a = __builtin_bit_cast(bf16x8, u);
            acc[mi][0] = __builtin_amdgcn_mfma_f32_16x16x32_bf16(a, wf0, acc[mi][0], 0, 0, 0);
            acc[mi][1] = __builtin_amdgcn_mfma_f32_16x16x32_bf16(a, wf1, acc[mi][1], 0, 0, 0);
        }
    };

    // ---- main loop: no barriers; chunk t+1's 32 loads in flight across chunk t ----
    issue(0, rawA);
    #pragma unroll
    for (int t = 0; t < 8; ++t) {
        if ((t & 1) == 0) {
            if (t < 7) issue(t + 1, rawB);
            step(t, rawA);
        } else {
            if (t < 7) issue(t + 1, rawA);
            step(t, rawB);
        }
    }

    // ---- reduce over positions: lane holds D[p = wave*64+mi*16+g*4+r][o = n*16+l15] ----
    float s[2]  = {0.f, 0.f};
    float mx[2] = {-3.0e38f, -3.0e38f};
    #pragma unroll
    for (int n = 0; n < 2; ++n) {
        #pragma unroll
        for (int mi = 0; mi < 4; ++mi) {
            #pragma unroll
            for (int r = 0; r < 4; ++r) {
                int pp = wave * 64 + mi * 16 + g * 4 + r;
                float v = acc[mi][n][r];
                if (pp < HW) { s[n] += v; mx[n] = fmaxf(mx[n], v); }
            }
        }
        s[n] += __shfl_xor(s[n], 16, 64);
        s[n] += __shfl_xor(s[n], 32, 64);
        mx[n] = fmaxf(mx[n], __shfl_xor(mx[n], 16, 64));
        mx[n] = fmaxf(mx[n], __shfl_xor(mx[n], 32, 64));
    }
    if (lane < 32) {
        lds_psum[lane][wave] = (lane < 16) ? s[0] : s[1];
        lds_pmax[lane][wave] = (lane < 16) ? mx[0] : mx[1];
    }
    __syncthreads();

    if (tid < C_HEAD) {
        float ss = 0.f, mm = -3.0e38f;
        #pragma unroll
        for (int w = 0; w < 6; ++w) { ss += lds_psum[tid][w]; mm = fmaxf(mm, lds_pmax[tid][w]); }
        float mean1 = ss * (1.0f / (float)HW);
        vp[tid]              = mean1;
        vp[C_HEAD + tid]     = mean1 * ((19.0f - 9.0f) * 0.1f);
        vp[2 * C_HEAD + tid] = mm;
    }
    __syncthreads();

    // ---- heads: wave 0 ----
    if (wave == 0) {
        const int j = lane;
        float h1 = 0.f, h3 = 0.f;
        if (j < CV) {
            float a1 = fc1_b[j], a3 = fc3_b[j], a4 = fc4_b[j];
            #pragma unroll
            for (int k = 0; k < 96; ++k) {
                float v = vp[k];
                a1 = fmaf(v, fc1_w[j * 96 + k], a1);
                a3 = fmaf(v, fc3_w[j * 96 + k], a3);
                a4 = fmaf(v, fc4_w[j * 97 + k], a4);
            }
            h1 = fmaxf(a1, 0.f) * fc2_w[j];
            h3 = fmaxf(a3, 0.f) * sc_w[j];
            base_l[j] = a4;
            dco_l[j]  = fc4_w[j * 97 + 96];
            f5_l[j]   = fc5_w[j];
        }
        float s1 = h1, s3 = h3;
        #pragma unroll
        for (int off = 32; off > 0; off >>= 1) {
            s1 += __shfl_xor(s1, off, 64);
            s3 += __shfl_xor(s3, off, 64);
        }
        float game = tanhf(s1 + fc2_b[0]);
        float scal = s3 + sc_b[0];
        if (lane == 0) out[b] = game;

        float z = -3.0e38f;
        if (lane < 41) {
            float dval = (float)(lane - 20);
            float lg = fc5_b[0];
            #pragma unroll
            for (int jj = 0; jj < CV; ++jj) {
                float t2 = fmaf(dval, dco_l[jj], base_l[jj]);
                t2 = fmaxf(t2, 0.f);
                lg = fmaf(t2, f5_l[jj], lg);
            }
            z = lg * scal;
        }
        float mz = z;
        #pragma unroll
        for (int off = 32; off > 0; off >>= 1) mz = fmaxf(mz, __shfl_xor(mz, off, 64));
        float e = (lane < 41) ? expf(z - mz) : 0.f;
        float se = e;
        #pragma unroll
        for (int off = 32; off > 0; off >>= 1) se += __shfl_xor(se, off, 64);
        if (lane < 41) out[B + b * 41 + lane] = e / se;
    }
}

extern "C" void kernel_launch(void* const* d_in, const int* in_sizes, int n_in,
                              void* d_out, int out_size, void* d_ws, size_t ws_size,
                              hipStream_t stream) {
    const float* x      = (const float*)d_in[0];
    const float* conv_w = (const float*)d_in[1];
    const float* fc1_w  = (const float*)d_in[2];
    const float* fc1_b  = (const float*)d_in[3];
    const float* fc2_w  = (const float*)d_in[4];
    const float* fc2_b  = (const float*)d_in[5];
    const float* fc3_w  = (const float*)d_in[6];
    const float* fc3_b  = (const float*)d_in[7];
    const float* sc_w   = (const float*)d_in[8];
    const float* sc_b   = (const float*)d_in[9];
    const float* fc4_w  = (const float*)d_in[10];
    const float* fc4_b  = (const float*)d_in[11];
    const float* fc5_w  = (const float*)d_in[12];
    const float* fc5_b  = (const float*)d_in[13];
    float* out = (float*)d_out;

    int B = in_sizes[0] / (C_IN * HW);

    vh_fused<<<dim3(B), dim3(NTHR), 0, stream>>>(
        x, conv_w, fc1_w, fc1_b, fc2_w, fc2_b, fc3_w, fc3_b,
        sc_w, sc_b, fc4_w, fc4_b, fc5_w, fc5_b, out, B);
}